// Round 4
// baseline (188.121 us; speedup 1.0000x reference)
//
#include <hip/hip_runtime.h>
#include <hip/hip_fp16.h>

// Problem constants: B=16, N=128, H=128, BD=64, P=256
using f16x4 = __attribute__((ext_vector_type(4))) _Float16;
using f32x4 = __attribute__((ext_vector_type(4))) float;

__device__ __forceinline__ f16x4 ld_f16x4(const void* p) {
    return *reinterpret_cast<const f16x4*>(p);
}

// ---------------------------------------------------------------------------
// Prep kernel A: W2bt[p][k] = W2[128+k][p] (f16, transposed), and
// W3 -> W3s (f16, transposed to [p][k], chunked by 32-k, XOR-swizzled so the
// main kernel can copy chunks linearly into LDS and read conflict-free).
// ---------------------------------------------------------------------------
__global__ void sp_wconv(const float* __restrict__ W2, const float* __restrict__ W3,
                         _Float16* __restrict__ W2bt, _Float16* __restrict__ W3s) {
    int t = blockIdx.x * 256 + threadIdx.x;   // grid covers 65536
    if (t < 16384) {
        int p = t >> 6, k = t & 63;
        W2bt[t] = (_Float16)W2[(128 + k) * 256 + p];
    }
    {
        // W3s flat index t -> (kc, p, slot', e); inverse swizzle: s = s' ^ (p&3)
        int kc = t >> 13, rem = t & 8191;
        int p = rem >> 5, q = rem & 31;
        int sp_ = q >> 3, e = q & 7;
        int s = sp_ ^ (p & 3);
        int k = kc * 32 + s * 8 + e;
        W3s[t] = (_Float16)W3[k * 256 + p];
    }
}

// ---------------------------------------------------------------------------
// Prep kernel B: hpartT[b][p][j] = hid[b,j,:] @ W2[0:128,p] + b2[p]  (fp32,
// TRANSPOSED so sp_main can read 4 consecutive j's as one float4).
// NOTE: hid[b,i,j] in the reference broadcasts hidden_states[b, j] (the
// NEIGHBOR's hidden state), so sp_main must add hpart of row j, not row i.
// ---------------------------------------------------------------------------
__global__ void sp_hpart(const float* __restrict__ hs, const float* __restrict__ W2,
                         const float* __restrict__ b2, float* __restrict__ hpartT) {
    __shared__ float sh[8 * 128];
    int rb = blockIdx.x * 8;           // 8 rows, all within one batch (8|128)
    int b = rb >> 7, j0 = rb & 127;
    int tid = threadIdx.x;
    for (int t = tid; t < 1024; t += 256) sh[t] = hs[rb * 128 + t];
    __syncthreads();
    float acc[8];
    float bb = b2[tid];
#pragma unroll
    for (int r = 0; r < 8; ++r) acc[r] = bb;
    for (int k = 0; k < 128; ++k) {
        float w = W2[k * 256 + tid];
#pragma unroll
        for (int r = 0; r < 8; ++r) acc[r] += sh[r * 128 + k] * w;
    }
#pragma unroll
    for (int r = 0; r < 8; ++r) hpartT[(b * 256 + tid) * 128 + j0 + r] = acc[r];
}

// ---------------------------------------------------------------------------
// Main kernel: one block per (b,i). 4 waves, wave w owns j-rows [32w,32w+32).
// Legacy mfma_f32_16x16x16f16 (A[m=l%16][k=4*(l/16)+e], B[k][n=l%16],
// D[m=4*(l/16)+r][n=l%16]).
//   enc (registers, f16 A-frags) -> T = enc @ W2bt (4 K-steps of 16)
//   U[j] = relu(hpartT[b,:,j] + T[j]) -> LDS (f16, 512B rows, XOR swizzle)
//   emb = U @ W3 (K=256: 8 chunks of 32, W3 chunk staged 16KB from ws)
//   pooled[p] = max_{j != i} emb[j,p] + b3[p]  -> d_out row bi (write-only)
// LDS: 64KB U + 16KB aux (W3 chunk / pool scratch) = 80KB -> 2 blocks/CU.
// ---------------------------------------------------------------------------
__global__ __launch_bounds__(256, 2) void sp_main(
    const float* __restrict__ pos, const float* __restrict__ W1,
    const float* __restrict__ b1, const float* __restrict__ b3,
    const float* __restrict__ hpartT, const _Float16* __restrict__ W2bt,
    const _Float16* __restrict__ W3s, float* __restrict__ pool) {
    __shared__ __align__(16) char smem[81920];
    char* sW3b   = smem + 65536;               // 16KB W3 chunk (phase 3)
    float* sPool = (float*)(smem + 65536);     // 4KB pool scratch (phase 4, aliased)

    const int bi = blockIdx.x;
    const int b = bi >> 7, i = bi & 127;
    const int tid = threadIdx.x;
    const int wave = tid >> 6, lane = tid & 63;
    const int l15 = lane & 15, lk = lane >> 4;

    const float pix = pos[(b * 128 + i) * 2 + 0];
    const float piy = pos[(b * 128 + i) * 2 + 1];

    // --- enc A-fragments straight into MFMA layout ------------------------
    // A[row][k]: row = l15 (+16*jt +32*wave), k = s*16 + lk*4 + e
    f16x4 aenc[2][4];
#pragma unroll
    for (int jt = 0; jt < 2; ++jt) {
        int j = wave * 32 + jt * 16 + l15;
        float rx = pos[(b * 128 + j) * 2 + 0] - pix;
        float ry = pos[(b * 128 + j) * 2 + 1] - piy;
#pragma unroll
        for (int s = 0; s < 4; ++s) {
            int k0 = s * 16 + lk * 4;
            f16x4 v;
#pragma unroll
            for (int e = 0; e < 4; ++e) {
                int k = k0 + e;
                float t = rx * W1[k] + ry * W1[64 + k] + b1[k];
                v[e] = (_Float16)(t > 0.f ? t : 0.f);
            }
            aenc[jt][s] = v;
        }
    }

    // --- T = enc @ W2b  (K=64 in 4 steps of 16) ---------------------------
    f32x4 acc[2][16];
#pragma unroll
    for (int jt = 0; jt < 2; ++jt)
#pragma unroll
        for (int pt = 0; pt < 16; ++pt) acc[jt][pt] = (f32x4){0.f, 0.f, 0.f, 0.f};

#pragma unroll
    for (int s = 0; s < 4; ++s) {
        int k0 = s * 16 + lk * 4;
#pragma unroll
        for (int pt = 0; pt < 16; ++pt) {
            int p = pt * 16 + l15;
            f16x4 bf = ld_f16x4(W2bt + p * 64 + k0);
            acc[0][pt] = __builtin_amdgcn_mfma_f32_16x16x16f16(aenc[0][s], bf, acc[0][pt], 0, 0, 0);
            acc[1][pt] = __builtin_amdgcn_mfma_f32_16x16x16f16(aenc[1][s], bf, acc[1][pt], 0, 0, 0);
        }
    }

    // --- U[j] = relu(hpartT[b,:,j] + T[j]) -> swizzled LDS -----------------
    // C/D layout: col(p) = l15 (+16*pt), row(j) = lk*4 + r (+16*jt +32*wave)
    // hpartT gives the 4 consecutive j's (r=0..3) as one float4.
    // U stored as 16B groups of 8 consecutive cols; group slot = (col>>3)^(row&7)
#pragma unroll
    for (int jt = 0; jt < 2; ++jt) {
        int row0 = wave * 32 + jt * 16 + lk * 4;
#pragma unroll
        for (int pt = 0; pt < 16; ++pt) {
            int col = pt * 16 + l15;
            f32x4 hp4 = *reinterpret_cast<const f32x4*>(
                hpartT + (b * 256 + col) * 128 + row0);
#pragma unroll
            for (int r = 0; r < 4; ++r) {
                int row = row0 + r;
                float v = acc[jt][pt][r] + hp4[r];
                v = v > 0.f ? v : 0.f;
                int slot = (col >> 3) ^ (row & 7);
                *(_Float16*)(smem + row * 512 + slot * 16 + (col & 7) * 2) = (_Float16)v;
            }
        }
    }
    __syncthreads();

    // --- emb = U @ W3, K=256 in 8 chunks of 32 (2 MFMA K-steps each) ------
    f32x4 eacc[2][16];
#pragma unroll
    for (int jt = 0; jt < 2; ++jt)
#pragma unroll
        for (int pt = 0; pt < 16; ++pt) eacc[jt][pt] = (f32x4){0.f, 0.f, 0.f, 0.f};

    const uint4* W3src = (const uint4*)W3s;
    uint4* W3dst = (uint4*)sW3b;
    for (int kc = 0; kc < 8; ++kc) {
        // stage 16KB chunk (pre-swizzled in ws, linear copy)
        const uint4* src = W3src + kc * 1024;
#pragma unroll
        for (int it = 0; it < 4; ++it) W3dst[tid + it * 256] = src[tid + it * 256];
        __syncthreads();

#pragma unroll
        for (int h = 0; h < 2; ++h) {
            int kl = h * 16 + lk * 4;          // chunk-local k, this lane's 4
            f16x4 af[2];
#pragma unroll
            for (int jt = 0; jt < 2; ++jt) {
                int row = wave * 32 + jt * 16 + l15;
                int g = kc * 4 + (kl >> 3);    // global k>>3
                int slot = g ^ (row & 7);
                af[jt] = ld_f16x4(smem + row * 512 + slot * 16 + (kl & 7) * 2);
            }
            int sp = kl >> 3;                  // chunk-local 16B group
#pragma unroll
            for (int pt = 0; pt < 16; ++pt) {
                int p = pt * 16 + l15;
                int bslot = sp ^ (p & 3);
                f16x4 bf = ld_f16x4(sW3b + p * 64 + bslot * 16 + (kl & 7) * 2);
                eacc[0][pt] = __builtin_amdgcn_mfma_f32_16x16x16f16(af[0], bf, eacc[0][pt], 0, 0, 0);
                eacc[1][pt] = __builtin_amdgcn_mfma_f32_16x16x16f16(af[1], bf, eacc[1][pt], 0, 0, 0);
            }
        }
        __syncthreads();
    }

    // --- masked max over j, cross-lane + cross-wave reduce ----------------
    float pm[16];
#pragma unroll
    for (int pt = 0; pt < 16; ++pt) {
        float m = -INFINITY;
#pragma unroll
        for (int jt = 0; jt < 2; ++jt) {
#pragma unroll
            for (int r = 0; r < 4; ++r) {
                int row = wave * 32 + jt * 16 + lk * 4 + r;
                float v = eacc[jt][pt][r];
                if (row != i) m = fmaxf(m, v);
            }
        }
        m = fmaxf(m, __shfl_xor(m, 16));
        m = fmaxf(m, __shfl_xor(m, 32));
        pm[pt] = m;
    }
    if (lane < 16) {
#pragma unroll
        for (int pt = 0; pt < 16; ++pt) sPool[wave * 256 + pt * 16 + lane] = pm[pt];
    }
    __syncthreads();
    {
        float v = fmaxf(fmaxf(sPool[tid], sPool[256 + tid]),
                        fmaxf(sPool[512 + tid], sPool[768 + tid]));
        pool[bi * 256 + tid] = v + b3[tid];    // d_out row bi (write-only)
    }
}

// ---------------------------------------------------------------------------
// Final: io = io @ Wout + bout, IN PLACE on d_out (16 rows per block; all 16
// rows staged to LDS behind a barrier before any write -> in-place safe).
// ---------------------------------------------------------------------------
__global__ void sp_out(const float* __restrict__ Wout, const float* __restrict__ bout,
                       float* __restrict__ io) {
    __shared__ float sp[16 * 256];
    int rb = blockIdx.x * 16;
    int tid = threadIdx.x;
    for (int t = tid; t < 4096; t += 256) sp[t] = io[rb * 256 + t];
    __syncthreads();
    float acc[16];
    float bb = bout[tid];
#pragma unroll
    for (int r = 0; r < 16; ++r) acc[r] = bb;
    for (int k = 0; k < 256; ++k) {
        float w = Wout[k * 256 + tid];
#pragma unroll
        for (int r = 0; r < 16; ++r) acc[r] += sp[r * 256 + k] * w;
    }
#pragma unroll
    for (int r = 0; r < 16; ++r) io[(rb + r) * 256 + tid] = acc[r];
}

extern "C" void kernel_launch(void* const* d_in, const int* in_sizes, int n_in,
                              void* d_out, int out_size, void* d_ws, size_t ws_size,
                              hipStream_t stream) {
    const float* hs   = (const float*)d_in[0];
    const float* pos  = (const float*)d_in[1];
    const float* W1   = (const float*)d_in[2];
    const float* b1   = (const float*)d_in[3];
    const float* W2   = (const float*)d_in[4];
    const float* b2   = (const float*)d_in[5];
    const float* W3   = (const float*)d_in[6];
    const float* b3   = (const float*)d_in[7];
    const float* Wout = (const float*)d_in[8];
    const float* bout = (const float*)d_in[9];
    float* out = (float*)d_out;

    // ws layout: hpartT 2MB | W2bt 32KB | W3s 128KB  (~2.2MB total)
    float*    hpartT = (float*)d_ws;
    _Float16* W2bt   = (_Float16*)((char*)d_ws + (1 << 21));
    _Float16* W3s    = (_Float16*)((char*)d_ws + (1 << 21) + 32768);

    sp_wconv<<<256, 256, 0, stream>>>(W2, W3, W2bt, W3s);
    sp_hpart<<<256, 256, 0, stream>>>(hs, W2, b2, hpartT);
    sp_main<<<2048, 256, 0, stream>>>(pos, W1, b1, b3, hpartT, W2bt, W3s, out);
    sp_out<<<128, 256, 0, stream>>>(Wout, bout, out);
}